// Round 8
// baseline (476.297 us; speedup 1.0000x reference)
//
#include <hip/hip_runtime.h>

// ChamferDistance: B=4, N=M=8192, fp32 3-D points.
// R8: two-orientation 32x32x16 bf16 MFMA (math verified R4/R5, absmax 0.0156)
//   A-form(p): [-2ph(3), -2pl(3), -2ph(3), nh, nl, 1, 1, 0,0,0]  (K=16)
//   B-form(p): [  ph(3),   ph(3),   pl(3),  1,  1, nh, nl, 0,0,0]
// R7 post-mortem: scratch traffic was a REGISTER-BUDGET spill, not lambdas.
// __launch_bounds__(256,4) caps the unified VGPR+AGPR file at 128/wave;
// live set (rmin 32 + 4 accs 64 + frags 24 + staging addr) ~136 -> allocator
// spilled the accumulators every stage (412 MB scratch writes). Fix: (256,3)
// -> 170 regs/wave. Split-K LDS layout already proved conflict-free (R7:
// SQ_LDS_BANK_CONFLICT 1.05M -> 0).

typedef short  short8 __attribute__((ext_vector_type(8)));
typedef float  f32x16 __attribute__((ext_vector_type(16)));

#define B_      4
#define NPT     8192
#define THREADS 256
#define ROWBLK  32               // 256-row blocks per (pass, batch)
#define NCHUNK  4                // col chunks -> grid = 2*4*32*4 = 1024
#define CCOLS   (NPT / NCHUNK)   // 2048 cols per chunk
#define STAGE_C 256              // cols per LDS stage (8 KB)
#define NSTAGE  (CCOLS / STAGE_C)
#define PINF_I  0x7f800000

__device__ __forceinline__ unsigned short f2bf(float x) {
    unsigned u = __float_as_uint(x);
    u += 0x7fff + ((u >> 16) & 1);
    return (unsigned short)(u >> 16);
}
__device__ __forceinline__ float bf2f(unsigned short b) {
    return __uint_as_float(((unsigned)b) << 16);
}
#define PK2(a, b) ((((unsigned)(b)) << 16) | (unsigned)(a))

__global__ __launch_bounds__(THREADS)
void cd_pack(const float* __restrict__ xyz1, const float* __restrict__ xyz2,
             unsigned short* __restrict__ A1, unsigned short* __restrict__ B1,
             unsigned short* __restrict__ A2, unsigned short* __restrict__ B2,
             int* __restrict__ out) {
    int i = blockIdx.x * THREADS + threadIdx.x;
    if (i >= B_ * NPT) return;
    const unsigned short one = 0x3f80;

    // B-form split-K placement: group g = i>>5, slot = i&31.
    //   uint4 idx for k0..7  : g*64 + slot
    //   uint4 idx for k8..15 : g*64 + 32 + slot
    const size_t bidx = ((size_t)(i >> 5)) * 64 + (i & 31);

    {   // cloud 1 -> A1 (linear) + B1 (split-K)
        float x0 = xyz1[3*i], x1 = xyz1[3*i+1], x2 = xyz1[3*i+2];
        unsigned short h0 = f2bf(x0), h1 = f2bf(x1), h2 = f2bf(x2);
        unsigned short l0 = f2bf(x0 - bf2f(h0)), l1 = f2bf(x1 - bf2f(h1)), l2 = f2bf(x2 - bf2f(h2));
        unsigned short m0 = f2bf(-2.f * bf2f(h0)), m1 = f2bf(-2.f * bf2f(h1)), m2 = f2bf(-2.f * bf2f(h2));
        unsigned short q0 = f2bf(-2.f * bf2f(l0)), q1 = f2bf(-2.f * bf2f(l1)), q2 = f2bf(-2.f * bf2f(l2));
        float n = x0*x0 + x1*x1 + x2*x2;
        unsigned short nh = f2bf(n), nl = f2bf(n - bf2f(nh));
        ((uint4*)A1)[(size_t)i * 2]     = make_uint4(PK2(m0, m1), PK2(m2, q0), PK2(q1, q2), PK2(m0, m1));
        ((uint4*)A1)[(size_t)i * 2 + 1] = make_uint4(PK2(m2, nh), PK2(nl, one), PK2(one, 0), PK2(0, 0));
        ((uint4*)B1)[bidx]      = make_uint4(PK2(h0, h1), PK2(h2, h0), PK2(h1, h2), PK2(l0, l1));
        ((uint4*)B1)[bidx + 32] = make_uint4(PK2(l2, one), PK2(one, nh), PK2(nl, 0), PK2(0, 0));
    }
    {   // cloud 2 -> A2 (linear) + B2 (split-K)
        float x0 = xyz2[3*i], x1 = xyz2[3*i+1], x2 = xyz2[3*i+2];
        unsigned short h0 = f2bf(x0), h1 = f2bf(x1), h2 = f2bf(x2);
        unsigned short l0 = f2bf(x0 - bf2f(h0)), l1 = f2bf(x1 - bf2f(h1)), l2 = f2bf(x2 - bf2f(h2));
        unsigned short m0 = f2bf(-2.f * bf2f(h0)), m1 = f2bf(-2.f * bf2f(h1)), m2 = f2bf(-2.f * bf2f(h2));
        unsigned short q0 = f2bf(-2.f * bf2f(l0)), q1 = f2bf(-2.f * bf2f(l1)), q2 = f2bf(-2.f * bf2f(l2));
        float n = x0*x0 + x1*x1 + x2*x2;
        unsigned short nh = f2bf(n), nl = f2bf(n - bf2f(nh));
        ((uint4*)A2)[(size_t)i * 2]     = make_uint4(PK2(m0, m1), PK2(m2, q0), PK2(q1, q2), PK2(m0, m1));
        ((uint4*)A2)[(size_t)i * 2 + 1] = make_uint4(PK2(m2, nh), PK2(nl, one), PK2(one, 0), PK2(0, 0));
        ((uint4*)B2)[bidx]      = make_uint4(PK2(h0, h1), PK2(h2, h0), PK2(h1, h2), PK2(l0, l1));
        ((uint4*)B2)[bidx + 32] = make_uint4(PK2(l2, one), PK2(one, nh), PK2(nl, 0), PK2(0, 0));
    }
    out[i] = PINF_I;
    out[(size_t)B_ * NPT + i] = PINF_I;
}

__global__ __launch_bounds__(THREADS, 3)    // 170 regs/wave: fits ~136 live, no spill
void cd_mfma32(const unsigned short* __restrict__ A1, const unsigned short* __restrict__ B1,
               const unsigned short* __restrict__ A2, const unsigned short* __restrict__ B2,
               int* __restrict__ out) {
    __shared__ unsigned short ysh[2][STAGE_C * 16];   // 2 x 8 KB

    int bid = blockIdx.x;
    const int c    = bid & (NCHUNK - 1);  bid >>= 2;
    const int rb   = bid & (ROWBLK - 1);  bid >>= 5;
    const int b    = bid & (B_ - 1);      bid >>= 2;
    const int pass = bid;                               // 0: dist1, 1: dist2

    const unsigned short* __restrict__ Ap = pass ? A2 : A1;
    const unsigned short* __restrict__ Bp = pass ? B1 : B2;
    int* __restrict__ o = out + (size_t)pass * B_ * NPT;

    const int tid  = threadIdx.x;
    const int lane = tid & 63;
    const int w    = tid >> 6;
    const int l31  = lane & 31;
    const int kg   = lane >> 5;            // k-half: k = kg*8 + idx

    const size_t bbase   = (size_t)b * NPT;
    const int    rowBase = rb * 256 + w * 64;

    // A fragments (linear layout), resident for the whole sweep
    short8 afrag0 = *(const short8*)(Ap + (bbase + rowBase +  0 + l31) * 16 + kg * 8);
    short8 afrag1 = *(const short8*)(Ap + (bbase + rowBase + 32 + l31) * 16 + kg * 8);

    f32x16 rmin0, rmin1;
    #pragma unroll
    for (int r = 0; r < 16; ++r) {
        rmin0[r] = __int_as_float(PINF_I);
        rmin1[r] = __int_as_float(PINF_I);
    }

    // B chunk base (split-K layout: 16 ushorts/pt, groups of 32 pts = 512 us)
    const unsigned short* gB = Bp + (bbase + (size_t)c * CCOLS) * 16;

    // Prologue: stage 0 into buffer 0 (linear 8 KB copy, 2x16B per thread)
    {
        const unsigned short* g0 = gB;
        #pragma unroll
        for (int r = 0; r < 2; ++r) {
            const unsigned short* gp = g0 + r * 2048 + w * 512 + lane * 8;
            unsigned short* lp = &ysh[0][r * 2048 + w * 512];
            __builtin_amdgcn_global_load_lds(
                (const __attribute__((address_space(1))) unsigned int*)gp,
                (__attribute__((address_space(3))) unsigned int*)lp, 16, 0, 0);
        }
    }
    __syncthreads();   // compiler emits s_waitcnt vmcnt(0) before s_barrier

    for (int s = 0; s < NSTAGE; ++s) {
        const int nb = s & 1;
        if (s + 1 < NSTAGE) {              // issue next stage; flies over MFMAs
            const unsigned short* g = gB + (size_t)(s + 1) * STAGE_C * 16;
            #pragma unroll
            for (int r = 0; r < 2; ++r) {
                const unsigned short* gp = g + r * 2048 + w * 512 + lane * 8;
                unsigned short* lp = &ysh[nb ^ 1][r * 2048 + w * 512];
                __builtin_amdgcn_global_load_lds(
                    (const __attribute__((address_space(1))) unsigned int*)gp,
                    (__attribute__((address_space(3))) unsigned int*)lp, 16, 0, 0);
            }
        }

        const unsigned short* bsh = &ysh[nb][0];
        #pragma unroll
        for (int p = 0; p < 4; ++p) {      // 64 cols per pair -> min3 fusion
            // split-K: group 2p at p*1024, group 2p+1 at p*1024+512 (ushorts)
            short8 bf0 = *(const short8*)(bsh + p * 1024 +       kg * 256 + l31 * 8);
            short8 bf1 = *(const short8*)(bsh + p * 1024 + 512 + kg * 256 + l31 * 8);
            f32x16 z = {0.f};
            f32x16 a00 = __builtin_amdgcn_mfma_f32_32x32x16_bf16(afrag0, bf0, z, 0, 0, 0);
            f32x16 a01 = __builtin_amdgcn_mfma_f32_32x32x16_bf16(afrag0, bf1, z, 0, 0, 0);
            #pragma unroll
            for (int r = 0; r < 16; ++r)
                rmin0[r] = fminf(fminf(a00[r], a01[r]), rmin0[r]);   // v_min3_f32
            f32x16 a10 = __builtin_amdgcn_mfma_f32_32x32x16_bf16(afrag1, bf0, z, 0, 0, 0);
            f32x16 a11 = __builtin_amdgcn_mfma_f32_32x32x16_bf16(afrag1, bf1, z, 0, 0, 0);
            #pragma unroll
            for (int r = 0; r < 16; ++r)
                rmin1[r] = fminf(fminf(a10[r], a11[r]), rmin1[r]);
        }

        if (s + 1 < NSTAGE) __syncthreads();   // drains vmcnt(0) + barrier
    }

    // Epilogue: butterfly row-mins across 32 col-slots, one atomic per row
    #pragma unroll
    for (int rt = 0; rt < 2; ++rt) {
        #pragma unroll
        for (int r = 0; r < 16; ++r) {
            float v = rt ? rmin1[r] : rmin0[r];
            v = fminf(v, __shfl_xor(v, 1, 64));
            v = fminf(v, __shfl_xor(v, 2, 64));
            v = fminf(v, __shfl_xor(v, 4, 64));
            v = fminf(v, __shfl_xor(v, 8, 64));
            v = fminf(v, __shfl_xor(v, 16, 64));
            if (l31 == 0) {
                int row = rowBase + rt * 32 + (r & 3) + 8 * (r >> 2) + 4 * kg;
                atomicMin(&o[bbase + row], __float_as_int(fmaxf(v, 0.f)));
            }
        }
    }
}

extern "C" void kernel_launch(void* const* d_in, const int* in_sizes, int n_in,
                              void* d_out, int out_size, void* d_ws, size_t ws_size,
                              hipStream_t stream) {
    const float* xyz1 = (const float*)d_in[0];
    const float* xyz2 = (const float*)d_in[1];

    const size_t PSZ = (size_t)B_ * NPT * 16;       // ushorts per packed array
    unsigned short* A1 = (unsigned short*)d_ws;     // 4 x 1 MB in d_ws
    unsigned short* B1 = A1 + PSZ;
    unsigned short* A2 = B1 + PSZ;
    unsigned short* B2 = A2 + PSZ;

    cd_pack<<<(B_ * NPT + THREADS - 1) / THREADS, THREADS, 0, stream>>>(
        xyz1, xyz2, A1, B1, A2, B2, (int*)d_out);

    cd_mfma32<<<2 * B_ * ROWBLK * NCHUNK, THREADS, 0, stream>>>(
        A1, B1, A2, B2, (int*)d_out);
}

// Round 9
// 60.099 us; speedup vs baseline: 7.9252x; 7.9252x over previous
//
#include <hip/hip_runtime.h>

// ChamferDistance: B=4, N=M=8192, fp32 3-D points.
// R9: two-orientation 32x32x16 bf16 MFMA (math verified R4/R5, absmax 0.0156)
//   A-form(p): [-2ph(3), -2pl(3), -2ph(3), nh, nl, 1, 1, 0,0,0]  (K=16)
//   B-form(p): [  ph(3),   ph(3),   pl(3),  1,  1, nh, nl, 0,0,0]
// R8 post-mortem: (256,3) is NOT a real occupancy point — gfx950 wave count
// steps at 64/128/256 VGPRs (m69), so the compiler rounded 3 waves/SIMD up to
// 4 -> same 128-reg cap as (256,4) -> same ~1KB/thread scratch spill
// (WRITE 264 MB = one frame/thread, FETCH 1.3 GB = refills). Fix: (256,2)
// -> 256-reg allocation point; live set ~150 fits. This is m97's proven
// regime (164+64 regs, 2 blocks/CU, same global_load_lds dbuf pattern).
// Prefetch (stage s+1 in flight over compute of s) hides latency, not TLP.

typedef short  short8 __attribute__((ext_vector_type(8)));
typedef float  f32x16 __attribute__((ext_vector_type(16)));

#define B_      4
#define NPT     8192
#define THREADS 256
#define ROWBLK  32               // 256-row blocks per (pass, batch)
#define NCHUNK  4                // col chunks -> grid = 2*4*32*4 = 1024
#define CCOLS   (NPT / NCHUNK)   // 2048 cols per chunk
#define STAGE_C 256              // cols per LDS stage (8 KB)
#define NSTAGE  (CCOLS / STAGE_C)
#define PINF_I  0x7f800000

__device__ __forceinline__ unsigned short f2bf(float x) {
    unsigned u = __float_as_uint(x);
    u += 0x7fff + ((u >> 16) & 1);
    return (unsigned short)(u >> 16);
}
__device__ __forceinline__ float bf2f(unsigned short b) {
    return __uint_as_float(((unsigned)b) << 16);
}
#define PK2(a, b) ((((unsigned)(b)) << 16) | (unsigned)(a))

__global__ __launch_bounds__(THREADS)
void cd_pack(const float* __restrict__ xyz1, const float* __restrict__ xyz2,
             unsigned short* __restrict__ A1, unsigned short* __restrict__ B1,
             unsigned short* __restrict__ A2, unsigned short* __restrict__ B2,
             int* __restrict__ out) {
    int i = blockIdx.x * THREADS + threadIdx.x;
    if (i >= B_ * NPT) return;
    const unsigned short one = 0x3f80;

    // B-form split-K placement: group g = i>>5, slot = i&31.
    //   uint4 idx for k0..7  : g*64 + slot
    //   uint4 idx for k8..15 : g*64 + 32 + slot
    const size_t bidx = ((size_t)(i >> 5)) * 64 + (i & 31);

    {   // cloud 1 -> A1 (linear) + B1 (split-K)
        float x0 = xyz1[3*i], x1 = xyz1[3*i+1], x2 = xyz1[3*i+2];
        unsigned short h0 = f2bf(x0), h1 = f2bf(x1), h2 = f2bf(x2);
        unsigned short l0 = f2bf(x0 - bf2f(h0)), l1 = f2bf(x1 - bf2f(h1)), l2 = f2bf(x2 - bf2f(h2));
        unsigned short m0 = f2bf(-2.f * bf2f(h0)), m1 = f2bf(-2.f * bf2f(h1)), m2 = f2bf(-2.f * bf2f(h2));
        unsigned short q0 = f2bf(-2.f * bf2f(l0)), q1 = f2bf(-2.f * bf2f(l1)), q2 = f2bf(-2.f * bf2f(l2));
        float n = x0*x0 + x1*x1 + x2*x2;
        unsigned short nh = f2bf(n), nl = f2bf(n - bf2f(nh));
        ((uint4*)A1)[(size_t)i * 2]     = make_uint4(PK2(m0, m1), PK2(m2, q0), PK2(q1, q2), PK2(m0, m1));
        ((uint4*)A1)[(size_t)i * 2 + 1] = make_uint4(PK2(m2, nh), PK2(nl, one), PK2(one, 0), PK2(0, 0));
        ((uint4*)B1)[bidx]      = make_uint4(PK2(h0, h1), PK2(h2, h0), PK2(h1, h2), PK2(l0, l1));
        ((uint4*)B1)[bidx + 32] = make_uint4(PK2(l2, one), PK2(one, nh), PK2(nl, 0), PK2(0, 0));
    }
    {   // cloud 2 -> A2 (linear) + B2 (split-K)
        float x0 = xyz2[3*i], x1 = xyz2[3*i+1], x2 = xyz2[3*i+2];
        unsigned short h0 = f2bf(x0), h1 = f2bf(x1), h2 = f2bf(x2);
        unsigned short l0 = f2bf(x0 - bf2f(h0)), l1 = f2bf(x1 - bf2f(h1)), l2 = f2bf(x2 - bf2f(h2));
        unsigned short m0 = f2bf(-2.f * bf2f(h0)), m1 = f2bf(-2.f * bf2f(h1)), m2 = f2bf(-2.f * bf2f(h2));
        unsigned short q0 = f2bf(-2.f * bf2f(l0)), q1 = f2bf(-2.f * bf2f(l1)), q2 = f2bf(-2.f * bf2f(l2));
        float n = x0*x0 + x1*x1 + x2*x2;
        unsigned short nh = f2bf(n), nl = f2bf(n - bf2f(nh));
        ((uint4*)A2)[(size_t)i * 2]     = make_uint4(PK2(m0, m1), PK2(m2, q0), PK2(q1, q2), PK2(m0, m1));
        ((uint4*)A2)[(size_t)i * 2 + 1] = make_uint4(PK2(m2, nh), PK2(nl, one), PK2(one, 0), PK2(0, 0));
        ((uint4*)B2)[bidx]      = make_uint4(PK2(h0, h1), PK2(h2, h0), PK2(h1, h2), PK2(l0, l1));
        ((uint4*)B2)[bidx + 32] = make_uint4(PK2(l2, one), PK2(one, nh), PK2(nl, 0), PK2(0, 0));
    }
    out[i] = PINF_I;
    out[(size_t)B_ * NPT + i] = PINF_I;
}

__global__ __launch_bounds__(THREADS, 2)    // 256-reg point: ~150 live fits, no spill
void cd_mfma32(const unsigned short* __restrict__ A1, const unsigned short* __restrict__ B1,
               const unsigned short* __restrict__ A2, const unsigned short* __restrict__ B2,
               int* __restrict__ out) {
    __shared__ unsigned short ysh[2][STAGE_C * 16];   // 2 x 8 KB

    int bid = blockIdx.x;
    const int c    = bid & (NCHUNK - 1);  bid >>= 2;
    const int rb   = bid & (ROWBLK - 1);  bid >>= 5;
    const int b    = bid & (B_ - 1);      bid >>= 2;
    const int pass = bid;                               // 0: dist1, 1: dist2

    const unsigned short* __restrict__ Ap = pass ? A2 : A1;
    const unsigned short* __restrict__ Bp = pass ? B1 : B2;
    int* __restrict__ o = out + (size_t)pass * B_ * NPT;

    const int tid  = threadIdx.x;
    const int lane = tid & 63;
    const int w    = tid >> 6;
    const int l31  = lane & 31;
    const int kg   = lane >> 5;            // k-half: k = kg*8 + idx

    const size_t bbase   = (size_t)b * NPT;
    const int    rowBase = rb * 256 + w * 64;

    // A fragments (linear layout), resident for the whole sweep
    short8 afrag0 = *(const short8*)(Ap + (bbase + rowBase +  0 + l31) * 16 + kg * 8);
    short8 afrag1 = *(const short8*)(Ap + (bbase + rowBase + 32 + l31) * 16 + kg * 8);

    f32x16 rmin0, rmin1;
    #pragma unroll
    for (int r = 0; r < 16; ++r) {
        rmin0[r] = __int_as_float(PINF_I);
        rmin1[r] = __int_as_float(PINF_I);
    }

    // B chunk base (split-K layout: 16 ushorts/pt, groups of 32 pts = 512 us)
    const unsigned short* gB = Bp + (bbase + (size_t)c * CCOLS) * 16;

    // Prologue: stage 0 into buffer 0 (linear 8 KB copy, 2x16B per thread)
    {
        const unsigned short* g0 = gB;
        #pragma unroll
        for (int r = 0; r < 2; ++r) {
            const unsigned short* gp = g0 + r * 2048 + w * 512 + lane * 8;
            unsigned short* lp = &ysh[0][r * 2048 + w * 512];
            __builtin_amdgcn_global_load_lds(
                (const __attribute__((address_space(1))) unsigned int*)gp,
                (__attribute__((address_space(3))) unsigned int*)lp, 16, 0, 0);
        }
    }
    __syncthreads();   // compiler emits s_waitcnt vmcnt(0) before s_barrier

    for (int s = 0; s < NSTAGE; ++s) {
        const int nb = s & 1;
        if (s + 1 < NSTAGE) {              // issue next stage; flies over MFMAs
            const unsigned short* g = gB + (size_t)(s + 1) * STAGE_C * 16;
            #pragma unroll
            for (int r = 0; r < 2; ++r) {
                const unsigned short* gp = g + r * 2048 + w * 512 + lane * 8;
                unsigned short* lp = &ysh[nb ^ 1][r * 2048 + w * 512];
                __builtin_amdgcn_global_load_lds(
                    (const __attribute__((address_space(1))) unsigned int*)gp,
                    (__attribute__((address_space(3))) unsigned int*)lp, 16, 0, 0);
            }
        }

        const unsigned short* bsh = &ysh[nb][0];
        #pragma unroll
        for (int p = 0; p < 4; ++p) {      // 64 cols per pair -> min3 fusion
            // split-K: group 2p at p*1024, group 2p+1 at p*1024+512 (ushorts)
            short8 bf0 = *(const short8*)(bsh + p * 1024 +       kg * 256 + l31 * 8);
            short8 bf1 = *(const short8*)(bsh + p * 1024 + 512 + kg * 256 + l31 * 8);
            f32x16 z = {0.f};
            f32x16 a00 = __builtin_amdgcn_mfma_f32_32x32x16_bf16(afrag0, bf0, z, 0, 0, 0);
            f32x16 a01 = __builtin_amdgcn_mfma_f32_32x32x16_bf16(afrag0, bf1, z, 0, 0, 0);
            #pragma unroll
            for (int r = 0; r < 16; ++r)
                rmin0[r] = fminf(fminf(a00[r], a01[r]), rmin0[r]);   // v_min3_f32
            f32x16 a10 = __builtin_amdgcn_mfma_f32_32x32x16_bf16(afrag1, bf0, z, 0, 0, 0);
            f32x16 a11 = __builtin_amdgcn_mfma_f32_32x32x16_bf16(afrag1, bf1, z, 0, 0, 0);
            #pragma unroll
            for (int r = 0; r < 16; ++r)
                rmin1[r] = fminf(fminf(a10[r], a11[r]), rmin1[r]);
        }

        if (s + 1 < NSTAGE) __syncthreads();   // drains vmcnt(0) + barrier
    }

    // Epilogue: butterfly row-mins across 32 col-slots, one atomic per row
    #pragma unroll
    for (int rt = 0; rt < 2; ++rt) {
        #pragma unroll
        for (int r = 0; r < 16; ++r) {
            float v = rt ? rmin1[r] : rmin0[r];
            v = fminf(v, __shfl_xor(v, 1, 64));
            v = fminf(v, __shfl_xor(v, 2, 64));
            v = fminf(v, __shfl_xor(v, 4, 64));
            v = fminf(v, __shfl_xor(v, 8, 64));
            v = fminf(v, __shfl_xor(v, 16, 64));
            if (l31 == 0) {
                int row = rowBase + rt * 32 + (r & 3) + 8 * (r >> 2) + 4 * kg;
                atomicMin(&o[bbase + row], __float_as_int(fmaxf(v, 0.f)));
            }
        }
    }
}

extern "C" void kernel_launch(void* const* d_in, const int* in_sizes, int n_in,
                              void* d_out, int out_size, void* d_ws, size_t ws_size,
                              hipStream_t stream) {
    const float* xyz1 = (const float*)d_in[0];
    const float* xyz2 = (const float*)d_in[1];

    const size_t PSZ = (size_t)B_ * NPT * 16;       // ushorts per packed array
    unsigned short* A1 = (unsigned short*)d_ws;     // 4 x 1 MB in d_ws
    unsigned short* B1 = A1 + PSZ;
    unsigned short* A2 = B1 + PSZ;
    unsigned short* B2 = A2 + PSZ;

    cd_pack<<<(B_ * NPT + THREADS - 1) / THREADS, THREADS, 0, stream>>>(
        xyz1, xyz2, A1, B1, A2, B2, (int*)d_out);

    cd_mfma32<<<2 * B_ * ROWBLK * NCHUNK, THREADS, 0, stream>>>(
        A1, B1, A2, B2, (int*)d_out);
}

// Round 10
// 37.751 us; speedup vs baseline: 12.6167x; 1.5920x over previous
//
#include <hip/hip_runtime.h>

// ChamferDistance: B=4, N=M=8192, fp32 3-D points.
// R10: back to the barrier-free streaming structure (R5, ~28 µs) + register
// prefetch. R9 post-mortem: LDS-staged variant had MfmaUtil 10.7%/VALUBusy 18%
// at 2 blocks/CU — per-stage barrier+vmcnt(0) lockstep at 2 waves/SIMD left
// ~80% stall; the no-barrier 4-waves/SIMD R5 was 2x faster despite 4x L2
// traffic. Latency tolerance > L2 traffic for this kernel.
//   - math (verified R4+, absmax 0.0156): d = n1+n2-2x.y as K=16 bf16 MFMA,
//     hi/lo compensated; two orientations so each pass's output is a pure
//     row-min in registers.
//   - B read directly from L2 in split-K layout (each wave instr = 1 KB
//     contiguous), one 32-col tile prefetched ahead in registers.
//   - no min3 pairing: keeps live set ~92 regs, safely under the 128 cap
//     at (256,4) = 4 blocks/CU (the R6-R8 spill cliff).

typedef short  short8 __attribute__((ext_vector_type(8)));
typedef float  f32x16 __attribute__((ext_vector_type(16)));

#define B_      4
#define NPT     8192
#define THREADS 256
#define ROWBLK  32               // 256-row blocks per (pass, batch)
#define NCHUNK  4                // col chunks -> grid = 2*4*32*4 = 1024 = 4/CU
#define CCOLS   (NPT / NCHUNK)   // 2048 cols per chunk
#define NTILE   (CCOLS / 32)     // 64 32-col tiles per chunk
#define PINF_I  0x7f800000

__device__ __forceinline__ unsigned short f2bf(float x) {
    unsigned u = __float_as_uint(x);
    u += 0x7fff + ((u >> 16) & 1);
    return (unsigned short)(u >> 16);
}
__device__ __forceinline__ float bf2f(unsigned short b) {
    return __uint_as_float(((unsigned)b) << 16);
}
#define PK2(a, b) ((((unsigned)(b)) << 16) | (unsigned)(a))

__global__ __launch_bounds__(THREADS)
void cd_pack(const float* __restrict__ xyz1, const float* __restrict__ xyz2,
             unsigned short* __restrict__ A1, unsigned short* __restrict__ B1,
             unsigned short* __restrict__ A2, unsigned short* __restrict__ B2,
             int* __restrict__ out) {
    int i = blockIdx.x * THREADS + threadIdx.x;
    if (i >= B_ * NPT) return;
    const unsigned short one = 0x3f80;

    // B-form split-K placement: group g = i>>5, slot = i&31.
    //   uint4 idx for k0..7  : g*64 + slot ; k8..15 : g*64 + 32 + slot
    const size_t bidx = ((size_t)(i >> 5)) * 64 + (i & 31);

    {   // cloud 1 -> A1 (linear) + B1 (split-K)
        float x0 = xyz1[3*i], x1 = xyz1[3*i+1], x2 = xyz1[3*i+2];
        unsigned short h0 = f2bf(x0), h1 = f2bf(x1), h2 = f2bf(x2);
        unsigned short l0 = f2bf(x0 - bf2f(h0)), l1 = f2bf(x1 - bf2f(h1)), l2 = f2bf(x2 - bf2f(h2));
        unsigned short m0 = f2bf(-2.f * bf2f(h0)), m1 = f2bf(-2.f * bf2f(h1)), m2 = f2bf(-2.f * bf2f(h2));
        unsigned short q0 = f2bf(-2.f * bf2f(l0)), q1 = f2bf(-2.f * bf2f(l1)), q2 = f2bf(-2.f * bf2f(l2));
        float n = x0*x0 + x1*x1 + x2*x2;
        unsigned short nh = f2bf(n), nl = f2bf(n - bf2f(nh));
        ((uint4*)A1)[(size_t)i * 2]     = make_uint4(PK2(m0, m1), PK2(m2, q0), PK2(q1, q2), PK2(m0, m1));
        ((uint4*)A1)[(size_t)i * 2 + 1] = make_uint4(PK2(m2, nh), PK2(nl, one), PK2(one, 0), PK2(0, 0));
        ((uint4*)B1)[bidx]      = make_uint4(PK2(h0, h1), PK2(h2, h0), PK2(h1, h2), PK2(l0, l1));
        ((uint4*)B1)[bidx + 32] = make_uint4(PK2(l2, one), PK2(one, nh), PK2(nl, 0), PK2(0, 0));
    }
    {   // cloud 2 -> A2 (linear) + B2 (split-K)
        float x0 = xyz2[3*i], x1 = xyz2[3*i+1], x2 = xyz2[3*i+2];
        unsigned short h0 = f2bf(x0), h1 = f2bf(x1), h2 = f2bf(x2);
        unsigned short l0 = f2bf(x0 - bf2f(h0)), l1 = f2bf(x1 - bf2f(h1)), l2 = f2bf(x2 - bf2f(h2));
        unsigned short m0 = f2bf(-2.f * bf2f(h0)), m1 = f2bf(-2.f * bf2f(h1)), m2 = f2bf(-2.f * bf2f(h2));
        unsigned short q0 = f2bf(-2.f * bf2f(l0)), q1 = f2bf(-2.f * bf2f(l1)), q2 = f2bf(-2.f * bf2f(l2));
        float n = x0*x0 + x1*x1 + x2*x2;
        unsigned short nh = f2bf(n), nl = f2bf(n - bf2f(nh));
        ((uint4*)A2)[(size_t)i * 2]     = make_uint4(PK2(m0, m1), PK2(m2, q0), PK2(q1, q2), PK2(m0, m1));
        ((uint4*)A2)[(size_t)i * 2 + 1] = make_uint4(PK2(m2, nh), PK2(nl, one), PK2(one, 0), PK2(0, 0));
        ((uint4*)B2)[bidx]      = make_uint4(PK2(h0, h1), PK2(h2, h0), PK2(h1, h2), PK2(l0, l1));
        ((uint4*)B2)[bidx + 32] = make_uint4(PK2(l2, one), PK2(one, nh), PK2(nl, 0), PK2(0, 0));
    }
    out[i] = PINF_I;
    out[(size_t)B_ * NPT + i] = PINF_I;
}

__global__ __launch_bounds__(THREADS, 4)    // live set ~92 regs < 128 cap
void cd_mfma32(const unsigned short* __restrict__ A1, const unsigned short* __restrict__ B1,
               const unsigned short* __restrict__ A2, const unsigned short* __restrict__ B2,
               int* __restrict__ out) {
    int bid = blockIdx.x;
    const int c    = bid & (NCHUNK - 1);  bid >>= 2;
    const int rb   = bid & (ROWBLK - 1);  bid >>= 5;
    const int b    = bid & (B_ - 1);      bid >>= 2;
    const int pass = bid;                               // 0: dist1, 1: dist2

    const unsigned short* __restrict__ Ap = pass ? A2 : A1;
    const unsigned short* __restrict__ Bp = pass ? B1 : B2;
    int* __restrict__ o = out + (size_t)pass * B_ * NPT;

    const int lane = threadIdx.x & 63;
    const int w    = threadIdx.x >> 6;
    const int l31  = lane & 31;
    const int kg   = lane >> 5;            // k-half: k = kg*8 + idx

    const size_t bbase   = (size_t)b * NPT;
    const int    rowBase = rb * 256 + w * 64;

    // A fragments (linear layout), resident for the whole sweep
    short8 afrag0 = *(const short8*)(Ap + (bbase + rowBase +  0 + l31) * 16 + kg * 8);
    short8 afrag1 = *(const short8*)(Ap + (bbase + rowBase + 32 + l31) * 16 + kg * 8);

    f32x16 rmin0, rmin1;
    #pragma unroll
    for (int r = 0; r < 16; ++r) {
        rmin0[r] = __int_as_float(PINF_I);
        rmin1[r] = __int_as_float(PINF_I);
    }

    // B chunk base, split-K: 32-pt group = 512 ushorts; lane reads
    // kg*256 + l31*8 -> each wave instruction covers a contiguous 1 KB.
    const unsigned short* __restrict__ gB =
        Bp + (bbase + (size_t)c * CCOLS) * 16 + kg * 256 + l31 * 8;

    short8 bfc = *(const short8*)(gB);          // tile 0
    #pragma unroll 2
    for (int t = 0; t < NTILE; ++t) {
        const int tn = (t + 1 < NTILE) ? t + 1 : t;     // clamp, branchless
        short8 bfn = *(const short8*)(gB + (size_t)tn * 512);   // prefetch

        f32x16 z = {0.f};
        f32x16 acc0 = __builtin_amdgcn_mfma_f32_32x32x16_bf16(afrag0, bfc, z, 0, 0, 0);
        f32x16 acc1 = __builtin_amdgcn_mfma_f32_32x32x16_bf16(afrag1, bfc, z, 0, 0, 0);
        #pragma unroll
        for (int r = 0; r < 16; ++r) rmin0[r] = fminf(rmin0[r], acc0[r]);
        #pragma unroll
        for (int r = 0; r < 16; ++r) rmin1[r] = fminf(rmin1[r], acc1[r]);

        bfc = bfn;
    }

    // Epilogue: butterfly row-mins across 32 col-slots, one atomic per row
    #pragma unroll
    for (int rt = 0; rt < 2; ++rt) {
        #pragma unroll
        for (int r = 0; r < 16; ++r) {
            float v = rt ? rmin1[r] : rmin0[r];
            v = fminf(v, __shfl_xor(v, 1, 64));
            v = fminf(v, __shfl_xor(v, 2, 64));
            v = fminf(v, __shfl_xor(v, 4, 64));
            v = fminf(v, __shfl_xor(v, 8, 64));
            v = fminf(v, __shfl_xor(v, 16, 64));
            if (l31 == 0) {
                int row = rowBase + rt * 32 + (r & 3) + 8 * (r >> 2) + 4 * kg;
                atomicMin(&o[bbase + row], __float_as_int(fmaxf(v, 0.f)));
            }
        }
    }
}

extern "C" void kernel_launch(void* const* d_in, const int* in_sizes, int n_in,
                              void* d_out, int out_size, void* d_ws, size_t ws_size,
                              hipStream_t stream) {
    const float* xyz1 = (const float*)d_in[0];
    const float* xyz2 = (const float*)d_in[1];

    const size_t PSZ = (size_t)B_ * NPT * 16;       // ushorts per packed array
    unsigned short* A1 = (unsigned short*)d_ws;     // 4 x 1 MB in d_ws
    unsigned short* B1 = A1 + PSZ;
    unsigned short* A2 = B1 + PSZ;
    unsigned short* B2 = A2 + PSZ;

    cd_pack<<<(B_ * NPT + THREADS - 1) / THREADS, THREADS, 0, stream>>>(
        xyz1, xyz2, A1, B1, A2, B2, (int*)d_out);

    cd_mfma32<<<2 * B_ * ROWBLK * NCHUNK, THREADS, 0, stream>>>(
        A1, B1, A2, B2, (int*)d_out);
}

// Round 11
// 37.119 us; speedup vs baseline: 12.8315x; 1.0170x over previous
//
#include <hip/hip_runtime.h>

// ChamferDistance: B=4, N=M=8192, fp32 3-D points.
// R11: 4-phase ping-pong register pipeline on the barrier-free streaming
// structure. R10 post-mortem: depth-1 prefetch (bfc=bfn rotation) forces
// vmcnt(0) + v_movs every iteration -> in-flight window ~85 cyc vs ~200-225
// cyc L2 latency -> same time as R5 (37.8). Fix: named regs bf0..bf3, each
// phase consumes bf_p then reloads it for tile t+4+p; consumer is 3 phases
// (~250 cyc) later, so compiler's in-order waits act as counted vmcnt(N).
// Register note: short8 = 4 VGPRs (was double-counted in R6-R8); live set
// ~98 regs fits (256,4)=128-reg cap. Math unchanged (verified since R4,
// absmax 0.0156): d = n1+n2-2x.y as K=16 bf16 MFMA, hi/lo compensated,
// two orientations, row-min pure in registers, int-punned atomicMin combine.

typedef short  short8 __attribute__((ext_vector_type(8)));
typedef float  f32x16 __attribute__((ext_vector_type(16)));

#define B_      4
#define NPT     8192
#define THREADS 256
#define ROWBLK  32               // 256-row blocks per (pass, batch)
#define NCHUNK  4                // col chunks -> grid = 2*4*32*4 = 1024 = 4/CU
#define CCOLS   (NPT / NCHUNK)   // 2048 cols per chunk
#define NTILE   (CCOLS / 32)     // 64 32-col tiles per chunk
#define PINF_I  0x7f800000

__device__ __forceinline__ unsigned short f2bf(float x) {
    unsigned u = __float_as_uint(x);
    u += 0x7fff + ((u >> 16) & 1);
    return (unsigned short)(u >> 16);
}
__device__ __forceinline__ float bf2f(unsigned short b) {
    return __uint_as_float(((unsigned)b) << 16);
}
#define PK2(a, b) ((((unsigned)(b)) << 16) | (unsigned)(a))

__global__ __launch_bounds__(THREADS)
void cd_pack(const float* __restrict__ xyz1, const float* __restrict__ xyz2,
             unsigned short* __restrict__ A1, unsigned short* __restrict__ B1,
             unsigned short* __restrict__ A2, unsigned short* __restrict__ B2,
             int* __restrict__ out) {
    int i = blockIdx.x * THREADS + threadIdx.x;
    if (i >= B_ * NPT) return;
    const unsigned short one = 0x3f80;

    // B-form split-K placement: group g = i>>5, slot = i&31.
    //   uint4 idx for k0..7  : g*64 + slot ; k8..15 : g*64 + 32 + slot
    const size_t bidx = ((size_t)(i >> 5)) * 64 + (i & 31);

    {   // cloud 1 -> A1 (linear) + B1 (split-K)
        float x0 = xyz1[3*i], x1 = xyz1[3*i+1], x2 = xyz1[3*i+2];
        unsigned short h0 = f2bf(x0), h1 = f2bf(x1), h2 = f2bf(x2);
        unsigned short l0 = f2bf(x0 - bf2f(h0)), l1 = f2bf(x1 - bf2f(h1)), l2 = f2bf(x2 - bf2f(h2));
        unsigned short m0 = f2bf(-2.f * bf2f(h0)), m1 = f2bf(-2.f * bf2f(h1)), m2 = f2bf(-2.f * bf2f(h2));
        unsigned short q0 = f2bf(-2.f * bf2f(l0)), q1 = f2bf(-2.f * bf2f(l1)), q2 = f2bf(-2.f * bf2f(l2));
        float n = x0*x0 + x1*x1 + x2*x2;
        unsigned short nh = f2bf(n), nl = f2bf(n - bf2f(nh));
        ((uint4*)A1)[(size_t)i * 2]     = make_uint4(PK2(m0, m1), PK2(m2, q0), PK2(q1, q2), PK2(m0, m1));
        ((uint4*)A1)[(size_t)i * 2 + 1] = make_uint4(PK2(m2, nh), PK2(nl, one), PK2(one, 0), PK2(0, 0));
        ((uint4*)B1)[bidx]      = make_uint4(PK2(h0, h1), PK2(h2, h0), PK2(h1, h2), PK2(l0, l1));
        ((uint4*)B1)[bidx + 32] = make_uint4(PK2(l2, one), PK2(one, nh), PK2(nl, 0), PK2(0, 0));
    }
    {   // cloud 2 -> A2 (linear) + B2 (split-K)
        float x0 = xyz2[3*i], x1 = xyz2[3*i+1], x2 = xyz2[3*i+2];
        unsigned short h0 = f2bf(x0), h1 = f2bf(x1), h2 = f2bf(x2);
        unsigned short l0 = f2bf(x0 - bf2f(h0)), l1 = f2bf(x1 - bf2f(h1)), l2 = f2bf(x2 - bf2f(h2));
        unsigned short m0 = f2bf(-2.f * bf2f(h0)), m1 = f2bf(-2.f * bf2f(h1)), m2 = f2bf(-2.f * bf2f(h2));
        unsigned short q0 = f2bf(-2.f * bf2f(l0)), q1 = f2bf(-2.f * bf2f(l1)), q2 = f2bf(-2.f * bf2f(l2));
        float n = x0*x0 + x1*x1 + x2*x2;
        unsigned short nh = f2bf(n), nl = f2bf(n - bf2f(nh));
        ((uint4*)A2)[(size_t)i * 2]     = make_uint4(PK2(m0, m1), PK2(m2, q0), PK2(q1, q2), PK2(m0, m1));
        ((uint4*)A2)[(size_t)i * 2 + 1] = make_uint4(PK2(m2, nh), PK2(nl, one), PK2(one, 0), PK2(0, 0));
        ((uint4*)B2)[bidx]      = make_uint4(PK2(h0, h1), PK2(h2, h0), PK2(h1, h2), PK2(l0, l1));
        ((uint4*)B2)[bidx + 32] = make_uint4(PK2(l2, one), PK2(one, nh), PK2(nl, 0), PK2(0, 0));
    }
    out[i] = PINF_I;
    out[(size_t)B_ * NPT + i] = PINF_I;
}

// One pipeline phase: 2 MFMA on bf, 32 running fmin, then reload bf with
// tile `tn` (clamped; tail re-reads last tile harmlessly). All static indices.
#define CD_PHASE(bf, tn)                                                        \
    {                                                                           \
        f32x16 z = {0.f};                                                       \
        f32x16 acc0 = __builtin_amdgcn_mfma_f32_32x32x16_bf16(afrag0, bf, z, 0, 0, 0); \
        _Pragma("unroll")                                                       \
        for (int r = 0; r < 16; ++r) rmin0[r] = fminf(rmin0[r], acc0[r]);       \
        f32x16 acc1 = __builtin_amdgcn_mfma_f32_32x32x16_bf16(afrag1, bf, z, 0, 0, 0); \
        _Pragma("unroll")                                                       \
        for (int r = 0; r < 16; ++r) rmin1[r] = fminf(rmin1[r], acc1[r]);       \
        int tt = (tn) < NTILE ? (tn) : NTILE - 1;                               \
        bf = *(const short8*)(gB + (size_t)tt * 512);                           \
    }

__global__ __launch_bounds__(THREADS, 4)    // live set ~98 regs < 128 cap
void cd_mfma32(const unsigned short* __restrict__ A1, const unsigned short* __restrict__ B1,
               const unsigned short* __restrict__ A2, const unsigned short* __restrict__ B2,
               int* __restrict__ out) {
    int bid = blockIdx.x;
    const int c    = bid & (NCHUNK - 1);  bid >>= 2;
    const int rb   = bid & (ROWBLK - 1);  bid >>= 5;
    const int b    = bid & (B_ - 1);      bid >>= 2;
    const int pass = bid;                               // 0: dist1, 1: dist2

    const unsigned short* __restrict__ Ap = pass ? A2 : A1;
    const unsigned short* __restrict__ Bp = pass ? B1 : B2;
    int* __restrict__ o = out + (size_t)pass * B_ * NPT;

    const int lane = threadIdx.x & 63;
    const int w    = threadIdx.x >> 6;
    const int l31  = lane & 31;
    const int kg   = lane >> 5;            // k-half: k = kg*8 + idx

    const size_t bbase   = (size_t)b * NPT;
    const int    rowBase = rb * 256 + w * 64;

    // A fragments (linear layout), resident for the whole sweep
    short8 afrag0 = *(const short8*)(Ap + (bbase + rowBase +  0 + l31) * 16 + kg * 8);
    short8 afrag1 = *(const short8*)(Ap + (bbase + rowBase + 32 + l31) * 16 + kg * 8);

    f32x16 rmin0, rmin1;
    #pragma unroll
    for (int r = 0; r < 16; ++r) {
        rmin0[r] = __int_as_float(PINF_I);
        rmin1[r] = __int_as_float(PINF_I);
    }

    // B chunk base, split-K: 32-pt group = 512 ushorts; lane reads
    // kg*256 + l31*8 -> each wave instruction covers a contiguous 1 KB.
    const unsigned short* __restrict__ gB =
        Bp + (bbase + (size_t)c * CCOLS) * 16 + kg * 256 + l31 * 8;

    // Prime the 4-deep pipeline
    short8 bf0 = *(const short8*)(gB);
    short8 bf1 = *(const short8*)(gB + 512);
    short8 bf2 = *(const short8*)(gB + 1024);
    short8 bf3 = *(const short8*)(gB + 1536);

    for (int t = 0; t < NTILE; t += 4) {
        CD_PHASE(bf0, t + 4)
        CD_PHASE(bf1, t + 5)
        CD_PHASE(bf2, t + 6)
        CD_PHASE(bf3, t + 7)
    }

    // Epilogue: butterfly row-mins across 32 col-slots, one atomic per row
    #pragma unroll
    for (int rt = 0; rt < 2; ++rt) {
        #pragma unroll
        for (int r = 0; r < 16; ++r) {
            float v = rt ? rmin1[r] : rmin0[r];
            v = fminf(v, __shfl_xor(v, 1, 64));
            v = fminf(v, __shfl_xor(v, 2, 64));
            v = fminf(v, __shfl_xor(v, 4, 64));
            v = fminf(v, __shfl_xor(v, 8, 64));
            v = fminf(v, __shfl_xor(v, 16, 64));
            if (l31 == 0) {
                int row = rowBase + rt * 32 + (r & 3) + 8 * (r >> 2) + 4 * kg;
                atomicMin(&o[bbase + row], __float_as_int(fmaxf(v, 0.f)));
            }
        }
    }
}

extern "C" void kernel_launch(void* const* d_in, const int* in_sizes, int n_in,
                              void* d_out, int out_size, void* d_ws, size_t ws_size,
                              hipStream_t stream) {
    const float* xyz1 = (const float*)d_in[0];
    const float* xyz2 = (const float*)d_in[1];

    const size_t PSZ = (size_t)B_ * NPT * 16;       // ushorts per packed array
    unsigned short* A1 = (unsigned short*)d_ws;     // 4 x 1 MB in d_ws
    unsigned short* B1 = A1 + PSZ;
    unsigned short* A2 = B1 + PSZ;
    unsigned short* B2 = A2 + PSZ;

    cd_pack<<<(B_ * NPT + THREADS - 1) / THREADS, THREADS, 0, stream>>>(
        xyz1, xyz2, A1, B1, A2, B2, (int*)d_out);

    cd_mfma32<<<2 * B_ * ROWBLK * NCHUNK, THREADS, 0, stream>>>(
        A1, B1, A2, B2, (int*)d_out);
}